// Round 22
// baseline (159.886 us; speedup 1.0000x reference)
//
#include <hip/hip_runtime.h>
#include <hip/hip_bf16.h>
#include <stdint.h>

typedef short s16x8 __attribute__((ext_vector_type(8)));
typedef float f32x4 __attribute__((ext_vector_type(4)));
typedef float f32x16 __attribute__((ext_vector_type(16)));
typedef unsigned short u16;
typedef unsigned int u32;

#define NB 4
#define NH 16
#define LSEQ 2048
#define EDIM 1024
#define HD 64
#define GM (NB*LSEQ)   // 8192
#define GK EDIM        // 1024
#define GN (NH*HD)     // 1024

// log2(e): folded into Q scale so softmax uses raw v_exp_f32 (= 2^x)
#define QSCALE 0.18033688011112042f   // 0.125 * log2(e)

__device__ __forceinline__ u16 f2bf(float f) {
  union { float f; uint32_t u; } v; v.f = f;
  uint32_t r = v.u + 0x7FFFu + ((v.u >> 16) & 1u);  // RNE
  return (u16)(r >> 16);
}

// v_cvt_pk_bf16_f32: two f32 -> packed 2x bf16 in one u32 (no builtin on gfx950)
__device__ __forceinline__ uint32_t cvtpk(float lo, float hi) {
  uint32_t r;
  asm("v_cvt_pk_bf16_f32 %0, %1, %2" : "=v"(r) : "v"(lo), "v"(hi));
  return r;
}

__device__ __forceinline__ float exp2f_fast(float x) {
  float r;
  asm("v_exp_f32 %0, %1" : "=v"(r) : "v"(x));
  return r;
}

// v_permlane32_swap_b32: swap upper 32 lanes of a with lower 32 lanes of b
__device__ __forceinline__ void pswap(u32 &a, u32 &b) {
  asm("v_permlane32_swap_b32 %0, %1" : "+v"(a), "+v"(b));
}

__device__ __forceinline__ void gload16(const void* g, void* l) {
  __builtin_amdgcn_global_load_lds((const __attribute__((address_space(1))) void*)g,
                                   (__attribute__((address_space(3))) void*)l, 16, 0, 0);
}

// ---------------- prep 1: mask compaction (blocks 0-3) + W converts (blocks 4+) ------
// Masked keys contribute EXACTLY 0 in the reference (exp(s-1e31-max) underflows
// f32) -> dropping them is exact. idx[b][0..nk) = unmasked key indices.
__global__ __launch_bounds__(256) void prep_w_mask(const int* __restrict__ m,
                                                   const float* __restrict__ w0,
                                                   const float* __restrict__ w1,
                                                   const float* __restrict__ w2,
                                                   u16* __restrict__ idx,
                                                   int* __restrict__ cnt,
                                                   u16* __restrict__ wt) {
  int blk = blockIdx.x;
  int t = threadIdx.x;
  if (blk < 4) {
    // ---- mask scan for batch blk ----
    __shared__ int sc[256];
    __shared__ int sbase[256];
    int b = blk;
    const int* mp = m + b*LSEQ;
    int loc[8]; int c = 0;
    #pragma unroll
    for (int j = 0; j < 8; ++j) { loc[j] = mp[t*8 + j]; c += (loc[j] != 0); }
    sc[t] = c;
    __syncthreads();
    if (t == 0) {
      int run = 0;
      for (int i = 0; i < 256; ++i) { sbase[i] = run; run += sc[i]; }
      cnt[b] = run;
      int nkp = (run + 127) & ~127;
      if (nkp < 128) nkp = 128;
      cnt[4 + b] = nkp;
    }
    __syncthreads();
    int base = sbase[t];
    #pragma unroll
    for (int j = 0; j < 8; ++j)
      if (loc[j]) idx[b*2048 + base++] = (u16)(t*8 + j);
  } else {
    // ---- W convert: [H][E][D] f32 -> Wt [p][H*D][E] bf16 (B^T layout) ----
    int i = (blk - 4) * 256 + t;            // 3*131072 total
    int p = i >> 17;
    const float* w = p == 0 ? w0 : (p == 1 ? w1 : w2);
    int n = (i >> 7) & 1023;
    int e0 = (i & 127) << 3;
    int h = n >> 6, d = n & 63;
    union { u16 u[8]; s16x8 v; } r;
    #pragma unroll
    for (int j = 0; j < 8; ++j)
      r.u[j] = f2bf(w[((size_t)h*EDIM + e0 + j)*HD + d]);
    *(s16x8*)(wt + (size_t)p*GN*GK + (size_t)n*EDIM + e0) = r.v;
  }
}

// ---------------- prep 2: Q convert + K gather + V gather (one launch) ---------------
__global__ __launch_bounds__(256) void prep_inputs(const float* __restrict__ q,
                                                   const float* __restrict__ k,
                                                   const float* __restrict__ v,
                                                   const u16* __restrict__ idx,
                                                   const int* __restrict__ cnt,
                                                   u16* __restrict__ qx,
                                                   u16* __restrict__ kx,
                                                   u16* __restrict__ vx) {
  int blk = blockIdx.x;
  int t = threadIdx.x;
  if (blk < 4096) {
    // Q convert: 8192*1024/8 elems
    int i = blk * 256 + t;
    const float4* p = (const float4*)(q + (size_t)i * 8);
    float4 a = p[0], bb = p[1];
    uint4 r;
    r.x = cvtpk(a.x, a.y); r.y = cvtpk(a.z, a.w);
    r.z = cvtpk(bb.x, bb.y); r.w = cvtpk(bb.z, bb.w);
    *(uint4*)(qx + (size_t)i*8) = r;
    return;
  }
  int seg = (blk - 4096) >> 12;              // 0 = K, 1 = V
  int i = ((blk - 4096) & 4095) * 256 + t;   // B*2048*128
  const float* x = seg ? v : k;
  u16* xb = seg ? vx : kx;
  int c = i & 127;
  int j = (i >> 7) & 2047;
  int b = i >> 18;
  int nk = cnt[b], nkp = cnt[4 + b];
  if (j >= nkp) return;
  u16* dst = xb + ((size_t)b*2048 + j)*EDIM + c*8;
  if (j < nk) {
    int sr = idx[b*2048 + j];
    const float4* p = (const float4*)(x + ((size_t)b*2048 + sr)*EDIM + c*8);
    float4 a = p[0], bb = p[1];
    uint4 r;
    r.x = cvtpk(a.x, a.y); r.y = cvtpk(a.z, a.w);
    r.z = cvtpk(bb.x, bb.y); r.w = cvtpk(bb.z, bb.w);
    *(uint4*)dst = r;
  } else {
    uint4 z = {0u, 0u, 0u, 0u};
    *(uint4*)dst = z;
  }
}

// ---------------- staging: 64-col bf16 tile, XOR-swizzled via pre-swizzled global src
// LDS[row][x] = G[row][x ^ ((row&7)<<4)]  (x = byte col, 16B granules; rule 21)
__device__ __forceinline__ void stage64(u16* dst, const u16* src, size_t ld,
                                        int iters, int t) {
  int r = t >> 3;
  int cb = (t & 7) << 4;
  for (int i = 0; i < iters; ++i) {
    int row = i*32 + r;
    int x = cb ^ ((row & 7) << 4);
    gload16(src + (size_t)row*ld + (x >> 1), dst + i*2048 + (t >> 6)*512);
  }
}

// ---------------- attn staging: paired-row layout [32 rows][256 B] -----------------
// Source tile: 64 rows x 128 B. LDS row r holds source rows {r, r+32}:
// LDS[r][x] = SRC[r + 32*(xs>=128)][xs & 127], xs = x ^ ((r&15)<<4).
__device__ __forceinline__ void stage256(u16* dst, const u16* src, size_t ld, int t) {
  #pragma unroll
  for (int i = 0; i < 2; ++i) {
    int o = i*4096 + t*16;
    int r = o >> 8;
    int s = (o >> 4) & 15;
    int xs = (s ^ (r & 15)) << 4;
    int row = r + ((xs >> 7) << 5);
    int db  = xs & 127;
    gload16(src + (size_t)row*ld + (db >> 1), dst + i*2048 + (t >> 6)*512);
  }
}

// ---------------- projection GEMM v3: z-batched {Q,K,V} in one launch ---------------
// Same r12 body (2-deep counted-vmcnt double-buffer, T3/T4); z selects operands.
// K/V (z>0): blocks whose 128-row M-tile is beyond nkp[b] exit immediately.
__global__ __launch_bounds__(256, 2) void gemm_proj3(const u16* __restrict__ qx,
                                                     const u16* __restrict__ kx,
                                                     const u16* __restrict__ vx,
                                                     const u16* __restrict__ Wt3,
                                                     const float* __restrict__ b0,
                                                     const float* __restrict__ b1,
                                                     const float* __restrict__ b2,
                                                     u16* __restrict__ o0,
                                                     u16* __restrict__ o1,
                                                     u16* __restrict__ o2,
                                                     const int* __restrict__ cnt) {
  int z = blockIdx.z;
  int m0 = blockIdx.x * 128, n0 = blockIdx.y * 128;
  if (z > 0) {
    int bb = m0 >> 11;
    if ((m0 & 2047) >= cnt[4 + bb]) return;   // dead compacted tile
  }
  const u16* A    = z == 0 ? qx : (z == 1 ? kx : vx);
  const u16* Bt   = Wt3 + (size_t)z * GN * GK;
  const float* bias = z == 0 ? b0 : (z == 1 ? b1 : b2);
  u16* outp       = z == 0 ? o0 : (z == 1 ? o1 : o2);
  float scale     = z == 0 ? QSCALE : 1.0f;
  int vmode       = (z == 2);

  __shared__ u16 Al[2][128*64];
  __shared__ u16 Bl[2][128*64];
  int t = threadIdx.x;
  int lane = t & 63, w = t >> 6;
  int wm = w >> 1, wn = w & 1;
  int g = lane >> 4, li = lane & 15;
  const u16* Ab0 = A + (size_t)m0 * GK;
  const u16* Bb0 = Bt + (size_t)n0 * GK;

  f32x4 acc[4][4];
  #pragma unroll
  for (int i = 0; i < 4; ++i)
    #pragma unroll
    for (int j = 0; j < 4; ++j) acc[i][j] = (f32x4){0.f,0.f,0.f,0.f};

  stage64(Al[0], Ab0,      GK, 4, t);
  stage64(Bl[0], Bb0,      GK, 4, t);
  stage64(Al[1], Ab0 + 64, GK, 4, t);
  stage64(Bl[1], Bb0 + 64, GK, 4, t);

  for (int kt = 0; kt < GK/64; ++kt) {
    int cur = kt & 1;
    if (kt < GK/64 - 1)
      asm volatile("s_waitcnt vmcnt(8)\n\ts_barrier" ::: "memory");
    else
      asm volatile("s_waitcnt vmcnt(0)\n\ts_barrier" ::: "memory");
    const u16* Ap = Al[cur];
    const u16* Bp = Bl[cur];
    #pragma unroll
    for (int kk = 0; kk < 2; ++kk) {
      s16x8 af[4], bfr[4];
      int cbase = kk*64 + (g << 4);
      #pragma unroll
      for (int mi = 0; mi < 4; ++mi) {
        int row = wm*64 + mi*16 + li;
        af[mi] = *(const s16x8*)(Ap + row*64 + ((cbase ^ ((row&7)<<4)) >> 1));
      }
      #pragma unroll
      for (int ni = 0; ni < 4; ++ni) {
        int row = wn*64 + ni*16 + li;
        bfr[ni] = *(const s16x8*)(Bp + row*64 + ((cbase ^ ((row&7)<<4)) >> 1));
      }
      #pragma unroll
      for (int mi = 0; mi < 4; ++mi)
        #pragma unroll
        for (int ni = 0; ni < 4; ++ni)
          acc[mi][ni] = __builtin_amdgcn_mfma_f32_16x16x32_bf16(af[mi], bfr[ni], acc[mi][ni], 0, 0, 0);
    }
    if (kt < GK/64 - 2) {
      asm volatile("s_barrier" ::: "memory");
      stage64(Al[cur], Ab0 + (kt+2)*64, GK, 4, t);
      stage64(Bl[cur], Bb0 + (kt+2)*64, GK, 4, t);
    }
  }

  #pragma unroll
  for (int ni = 0; ni < 4; ++ni) {
    int n = n0 + wn*64 + ni*16 + li;
    float bv = bias[n];
    int h = n >> 6, d = n & 63;
    #pragma unroll
    for (int mi = 0; mi < 4; ++mi) {
      int mrow = m0 + wm*64 + mi*16 + (g << 2);
      int bi = mrow >> 11, lr = mrow & 2047;
      if (!vmode) {
        u16* o = outp + ((size_t)(bi*NH + h)*LSEQ + lr)*HD + d;
        #pragma unroll
        for (int r2 = 0; r2 < 4; ++r2)
          o[(size_t)r2*HD] = f2bf((acc[mi][ni][r2] + bv) * scale);
      } else {
        u16* o = outp + ((size_t)(bi*NH + h)*HD + d)*LSEQ + lr;
        uint2 pk;
        pk.x = cvtpk((acc[mi][ni][0] + bv) * scale, (acc[mi][ni][1] + bv) * scale);
        pk.y = cvtpk((acc[mi][ni][2] + bv) * scale, (acc[mi][ni][3] + bv) * scale);
        *(uint2*)o = pk;
      }
    }
  }
}

// ---------------- flash attention v14: KVBLK=128 (sync events halved) ---------------
// r21 core (32x32 MFMA, in-reg P T12, setprio T5, counted-vmcnt T4, paired-row
// LDS, compacted keys, XCD-local grid). Each 128-key tile = two 64-key subtiles
// staged into one buffer; ONE vmcnt(8) wait + TWO barriers per 128 keys (was per
// 64). Sub loop is unroll-1 so per-sub register state (S/ak/av/pb) is reused —
// VGPR stays ~84 under the (256,3) cap. LDS 64 KB -> 2 blocks/CU (= measured
// residency anyway). nkp is a multiple of 128 -> nt1 = nkp/128 >= 1.
__global__ __launch_bounds__(256, 3) void attn_kernel(const u16* __restrict__ Qb,
                                                      const u16* __restrict__ Kb,
                                                      const u16* __restrict__ Vt,
                                                      const int* __restrict__ cnt,
                                                      float* __restrict__ out) {
  __shared__ u16 Kl[2][2][64*64];
  __shared__ u16 Vl[2][2][64*64];
  int t = threadIdx.x;
  int lane = t & 63, w = t >> 6;
  int q = lane & 31, hi = lane >> 5;
  int bh = blockIdx.x, b = bh >> 4, h = bh & 15;   // T1: bh fastest -> same-KV
  int q0 = blockIdx.y * 128;                       //     blocks land on one XCD
  int nk  = cnt[b];
  int nkp = cnt[4 + b];
  int nt1 = nkp >> 7;                        // 128-key tiles, >= 1
  const u16* Qp = Qb + (size_t)bh * LSEQ * HD;
  const u16* Kp = Kb + (size_t)bh * LSEQ * HD;
  const u16* Vp = Vt + (size_t)bh * HD * LSEQ;

  int qrow = q0 + w*32 + q;
  s16x8 bq[4];
  #pragma unroll
  for (int ks = 0; ks < 4; ++ks)
    bq[ks] = *(const s16x8*)(Qp + (size_t)qrow*HD + ks*16 + hi*8);

  float lsum = 0.f;
  f32x16 acco[2];
  #pragma unroll
  for (int dt = 0; dt < 2; ++dt) acco[dt] = (f32x16){0.f};

  // paired-row frag offsets: byte = q*256 + ((half*128 + ks*32 + hi*16) ^ ((q&15)<<4))
  int koff[2][4];
  {
    int swz = (q & 15) << 4;
    #pragma unroll
    for (int half = 0; half < 2; ++half)
      #pragma unroll
      for (int ks = 0; ks < 4; ++ks)
        koff[half][ks] = q*256 + ((half*128 + ks*32 + hi*16) ^ swz);
  }

  // stage one 128-key tile (two 64-key subtiles) into buffer buf: 8 loads/thread
  auto stageTile = [&](int buf, int t0) {
    stage256(Kl[buf][0], Kp + (size_t)t0*HD,        HD,   t);
    stage256(Kl[buf][1], Kp + (size_t)(t0+64)*HD,   HD,   t);
    stage256(Vl[buf][0], Vp + t0,                   LSEQ, t);
    stage256(Vl[buf][1], Vp + t0 + 64,              LSEQ, t);
  };

  // prologue: 2-deep prefetch. FIFO/thread: [tile0:8][tile1:8]
  stageTile(0, 0);
  if (nt1 > 1) stageTile(1, 128);

  auto body = [&](int tt, bool last) {
    int cur = tt & 1;

    if (last)
      asm volatile("s_waitcnt vmcnt(0)\n\ts_barrier" ::: "memory");
    else
      asm volatile("s_waitcnt vmcnt(8)\n\ts_barrier" ::: "memory");

    #pragma unroll 1
    for (int sub = 0; sub < 2; ++sub) {
      int t0 = tt*128 + sub*64;
      const char* Kc = (const char*)Kl[cur][sub];
      const char* Vc = (const char*)Vl[cur][sub];

      s16x8 ak[2][4];
      #pragma unroll
      for (int kt = 0; kt < 2; ++kt)
        #pragma unroll
        for (int ks = 0; ks < 4; ++ks)
          ak[kt][ks] = *(const s16x8*)(Kc + koff[kt][ks]);

      f32x16 S[2];
      __builtin_amdgcn_s_setprio(1);
      #pragma unroll
      for (int kt = 0; kt < 2; ++kt) {
        f32x16 z = {0.f};
        z = __builtin_amdgcn_mfma_f32_32x32x16_bf16(ak[kt][0], bq[0], z, 0, 0, 0);
        z = __builtin_amdgcn_mfma_f32_32x32x16_bf16(ak[kt][1], bq[1], z, 0, 0, 0);
        z = __builtin_amdgcn_mfma_f32_32x32x16_bf16(ak[kt][2], bq[2], z, 0, 0, 0);
        S[kt] = __builtin_amdgcn_mfma_f32_32x32x16_bf16(ak[kt][3], bq[3], z, 0, 0, 0);
      }
      __builtin_amdgcn_s_setprio(0);

      s16x8 av[2][4];
      #pragma unroll
      for (int dt = 0; dt < 2; ++dt)
        #pragma unroll
        for (int ks = 0; ks < 4; ++ks)
          av[dt][ks] = *(const s16x8*)(Vc + koff[dt][ks]);

      // softmax: p = exp2(S); tail subtiles zero pad keys via kA < nk
      bool nm = (t0 + 64 > nk);
      s16x8 pb[4];
      #pragma unroll
      for (int kt = 0; kt < 2; ++kt) {
        float p[16];
        #pragma unroll
        for (int r = 0; r < 16; ++r) {
          float e = exp2f_fast(S[kt][r]);
          if (nm) {
            int kA = t0 + kt*32 + ((r>>2)<<3) + (r&3) + (hi<<2);
            e = (kA < nk) ? e : 0.f;
          }
          p[r] = e;
        }
        float a0 = (p[0]+p[1])+(p[2]+p[3]);
        float a1 = (p[4]+p[5])+(p[6]+p[7]);
        float a2 = (p[8]+p[9])+(p[10]+p[11]);
        float a3 = (p[12]+p[13])+(p[14]+p[15]);
        lsum += (a0+a1)+(a2+a3);
        u32 w0 = cvtpk(p[0],  p[1]),  w1 = cvtpk(p[2],  p[3]);
        u32 w2 = cvtpk(p[4],  p[5]),  w3 = cvtpk(p[6],  p[7]);
        u32 w4 = cvtpk(p[8],  p[9]),  w5 = cvtpk(p[10], p[11]);
        u32 w6 = cvtpk(p[12], p[13]), w7 = cvtpk(p[14], p[15]);
        pswap(w0, w2); pswap(w1, w3);    // slice 2kt:   keys hi*8 + 0..7
        pswap(w4, w6); pswap(w5, w7);    // slice 2kt+1: keys 16 + hi*8 + 0..7
        union { u32 u[4]; s16x8 v; } f0, f1;
        f0.u[0] = w0; f0.u[1] = w1; f0.u[2] = w2; f0.u[3] = w3;
        f1.u[0] = w4; f1.u[1] = w5; f1.u[2] = w6; f1.u[3] = w7;
        pb[2*kt]   = f0.v;
        pb[2*kt+1] = f1.v;
      }

      __builtin_amdgcn_s_setprio(1);
      #pragma unroll
      for (int dt = 0; dt < 2; ++dt) {
        #pragma unroll
        for (int ks = 0; ks < 4; ++ks)
          acco[dt] = __builtin_amdgcn_mfma_f32_32x32x16_bf16(av[dt][ks], pb[ks], acco[dt], 0, 0, 0);
      }
      __builtin_amdgcn_s_setprio(0);
    }

    if (!last) {
      if (tt + 2 < nt1) {
        asm volatile("s_barrier" ::: "memory");   // all waves done with buf[cur]
        stageTile(cur, (tt + 2) * 128);
      }
    }
  };

  for (int tt = 0; tt < nt1 - 1; ++tt) body(tt, false);
  body(nt1 - 1, true);

  float tot = lsum + __shfl_xor(lsum, 32);
  float inv = 1.0f / tot;
  float* op = out + ((size_t)b*LSEQ + qrow)*GN + h*HD;
  #pragma unroll
  for (int dt = 0; dt < 2; ++dt)
    #pragma unroll
    for (int rb = 0; rb < 4; ++rb) {
      float4 o;
      o.x = acco[dt][4*rb+0]*inv; o.y = acco[dt][4*rb+1]*inv;
      o.z = acco[dt][4*rb+2]*inv; o.w = acco[dt][4*rb+3]*inv;
      *(float4*)(op + dt*32 + rb*8 + hi*4) = o;
    }
}

// ---------------- host ----------------
extern "C" void kernel_launch(void* const* d_in, const int* in_sizes, int n_in,
                              void* d_out, int out_size, void* d_ws, size_t ws_size,
                              hipStream_t stream) {
  const float* query = (const float*)d_in[0];
  const float* key   = (const float*)d_in[1];
  const float* value = (const float*)d_in[2];
  const int*   masks = (const int*)d_in[3];
  const float* Wq = (const float*)d_in[4];
  const float* bq = (const float*)d_in[5];
  const float* Wk = (const float*)d_in[6];
  const float* bk = (const float*)d_in[7];
  const float* Wv = (const float*)d_in[8];
  const float* bv = (const float*)d_in[9];
  float* out = (float*)d_out;

  char* ws = (char*)d_ws;
  u16* qx  = (u16*)ws;                        // 16777216 B  Q bf16 [B,L,E]
  u16* kx  = (u16*)(ws + 16777216);           // 16777216 B  K bf16 compacted rows
  u16* wt3 = (u16*)(ws + 33554432);           //  6291456 B  [3][1024][1024] bf16
  u16* qb  = (u16*)(ws + 39845888);           // 16777216 B  [B,H,L,D]
  u16* kb  = (u16*)(ws + 56623104);           // 16777216 B  [B,H,L,D] (compacted)
  u16* vt  = (u16*)(ws + 73400320);           // 16777216 B  [B,H,D,L] (compacted)
  u16* vx  = (u16*)(ws + 90177536);           // 16777216 B  V bf16 compacted rows
  u16* idx = (u16*)(ws + 106954752);          //    16384 B  [4][2048]
  int* cnt = (int*)(ws + 106971136);          //       32 B  nk[4], nkp[4]
  (void)ws_size;

  prep_w_mask<<<4 + 1536, 256, 0, stream>>>(masks, Wq, Wk, Wv, idx, cnt, wt3);
  prep_inputs<<<4096 + 8192, 256, 0, stream>>>(query, key, value, idx, cnt,
                                               qx, kx, vx);
  gemm_proj3<<<dim3(GM/128, GN/128, 3), 256, 0, stream>>>(qx, kx, vx, wt3,
                                                          bq, bk, bv,
                                                          qb, kb, vt, cnt);
  attn_kernel<<<dim3(NB*NH, LSEQ/128), 256, 0, stream>>>(qb, kb, vt, cnt, out);
}

// Round 23
// 153.504 us; speedup vs baseline: 1.0416x; 1.0416x over previous
//
#include <hip/hip_runtime.h>
#include <hip/hip_bf16.h>
#include <stdint.h>

typedef short s16x8 __attribute__((ext_vector_type(8)));
typedef float f32x4 __attribute__((ext_vector_type(4)));
typedef float f32x16 __attribute__((ext_vector_type(16)));
typedef unsigned short u16;
typedef unsigned int u32;

#define NB 4
#define NH 16
#define LSEQ 2048
#define EDIM 1024
#define HD 64
#define GM (NB*LSEQ)   // 8192
#define GK EDIM        // 1024
#define GN (NH*HD)     // 1024

// log2(e): folded into Q scale so softmax uses raw v_exp_f32 (= 2^x)
#define QSCALE 0.18033688011112042f   // 0.125 * log2(e)

__device__ __forceinline__ u16 f2bf(float f) {
  union { float f; uint32_t u; } v; v.f = f;
  uint32_t r = v.u + 0x7FFFu + ((v.u >> 16) & 1u);  // RNE
  return (u16)(r >> 16);
}

// v_cvt_pk_bf16_f32: two f32 -> packed 2x bf16 in one u32 (no builtin on gfx950)
__device__ __forceinline__ uint32_t cvtpk(float lo, float hi) {
  uint32_t r;
  asm("v_cvt_pk_bf16_f32 %0, %1, %2" : "=v"(r) : "v"(lo), "v"(hi));
  return r;
}

__device__ __forceinline__ float exp2f_fast(float x) {
  float r;
  asm("v_exp_f32 %0, %1" : "=v"(r) : "v"(x));
  return r;
}

// v_permlane32_swap_b32: swap upper 32 lanes of a with lower 32 lanes of b
__device__ __forceinline__ void pswap(u32 &a, u32 &b) {
  asm("v_permlane32_swap_b32 %0, %1" : "+v"(a), "+v"(b));
}

__device__ __forceinline__ void gload16(const void* g, void* l) {
  __builtin_amdgcn_global_load_lds((const __attribute__((address_space(1))) void*)g,
                                   (__attribute__((address_space(3))) void*)l, 16, 0, 0);
}

// ---------------- prep 1: mask compaction (blocks 0-3) + W converts (blocks 4+) ------
// Masked keys contribute EXACTLY 0 in the reference (exp(s-1e31-max) underflows
// f32) -> dropping them is exact. idx[b][0..nk) = unmasked key indices.
__global__ __launch_bounds__(256) void prep_w_mask(const int* __restrict__ m,
                                                   const float* __restrict__ w0,
                                                   const float* __restrict__ w1,
                                                   const float* __restrict__ w2,
                                                   u16* __restrict__ idx,
                                                   int* __restrict__ cnt,
                                                   u16* __restrict__ wt) {
  int blk = blockIdx.x;
  int t = threadIdx.x;
  if (blk < 4) {
    // ---- mask scan for batch blk ----
    __shared__ int sc[256];
    __shared__ int sbase[256];
    int b = blk;
    const int* mp = m + b*LSEQ;
    int loc[8]; int c = 0;
    #pragma unroll
    for (int j = 0; j < 8; ++j) { loc[j] = mp[t*8 + j]; c += (loc[j] != 0); }
    sc[t] = c;
    __syncthreads();
    if (t == 0) {
      int run = 0;
      for (int i = 0; i < 256; ++i) { sbase[i] = run; run += sc[i]; }
      cnt[b] = run;
      int nkp = (run + 127) & ~127;
      if (nkp < 128) nkp = 128;
      cnt[4 + b] = nkp;
    }
    __syncthreads();
    int base = sbase[t];
    #pragma unroll
    for (int j = 0; j < 8; ++j)
      if (loc[j]) idx[b*2048 + base++] = (u16)(t*8 + j);
  } else {
    // ---- W convert: [H][E][D] f32 -> Wt [p][H*D][E] bf16 (B^T layout) ----
    int i = (blk - 4) * 256 + t;            // 3*131072 total
    int p = i >> 17;
    const float* w = p == 0 ? w0 : (p == 1 ? w1 : w2);
    int n = (i >> 7) & 1023;
    int e0 = (i & 127) << 3;
    int h = n >> 6, d = n & 63;
    union { u16 u[8]; s16x8 v; } r;
    #pragma unroll
    for (int j = 0; j < 8; ++j)
      r.u[j] = f2bf(w[((size_t)h*EDIM + e0 + j)*HD + d]);
    *(s16x8*)(wt + (size_t)p*GN*GK + (size_t)n*EDIM + e0) = r.v;
  }
}

// ---------------- prep 2: Q convert + K gather + V gather (one launch) ---------------
__global__ __launch_bounds__(256) void prep_inputs(const float* __restrict__ q,
                                                   const float* __restrict__ k,
                                                   const float* __restrict__ v,
                                                   const u16* __restrict__ idx,
                                                   const int* __restrict__ cnt,
                                                   u16* __restrict__ qx,
                                                   u16* __restrict__ kx,
                                                   u16* __restrict__ vx) {
  int blk = blockIdx.x;
  int t = threadIdx.x;
  if (blk < 4096) {
    // Q convert: 8192*1024/8 elems
    int i = blk * 256 + t;
    const float4* p = (const float4*)(q + (size_t)i * 8);
    float4 a = p[0], bb = p[1];
    uint4 r;
    r.x = cvtpk(a.x, a.y); r.y = cvtpk(a.z, a.w);
    r.z = cvtpk(bb.x, bb.y); r.w = cvtpk(bb.z, bb.w);
    *(uint4*)(qx + (size_t)i*8) = r;
    return;
  }
  int seg = (blk - 4096) >> 12;              // 0 = K, 1 = V
  int i = ((blk - 4096) & 4095) * 256 + t;   // B*2048*128
  const float* x = seg ? v : k;
  u16* xb = seg ? vx : kx;
  int c = i & 127;
  int j = (i >> 7) & 2047;
  int b = i >> 18;
  int nk = cnt[b], nkp = cnt[4 + b];
  if (j >= nkp) return;
  u16* dst = xb + ((size_t)b*2048 + j)*EDIM + c*8;
  if (j < nk) {
    int sr = idx[b*2048 + j];
    const float4* p = (const float4*)(x + ((size_t)b*2048 + sr)*EDIM + c*8);
    float4 a = p[0], bb = p[1];
    uint4 r;
    r.x = cvtpk(a.x, a.y); r.y = cvtpk(a.z, a.w);
    r.z = cvtpk(bb.x, bb.y); r.w = cvtpk(bb.z, bb.w);
    *(uint4*)dst = r;
  } else {
    uint4 z = {0u, 0u, 0u, 0u};
    *(uint4*)dst = z;
  }
}

// ---------------- staging: 64-col bf16 tile, XOR-swizzled via pre-swizzled global src
// LDS[row][x] = G[row][x ^ ((row&7)<<4)]  (x = byte col, 16B granules; rule 21)
__device__ __forceinline__ void stage64(u16* dst, const u16* src, size_t ld,
                                        int iters, int t) {
  int r = t >> 3;
  int cb = (t & 7) << 4;
  for (int i = 0; i < iters; ++i) {
    int row = i*32 + r;
    int x = cb ^ ((row & 7) << 4);
    gload16(src + (size_t)row*ld + (x >> 1), dst + i*2048 + (t >> 6)*512);
  }
}

// ---------------- attn staging: paired-row layout [32 rows][256 B] -----------------
// Source tile: 64 rows x 128 B. LDS row r holds source rows {r, r+32}:
// LDS[r][x] = SRC[r + 32*(xs>=128)][xs & 127], xs = x ^ ((r&15)<<4).
__device__ __forceinline__ void stage256(u16* dst, const u16* src, size_t ld, int t) {
  #pragma unroll
  for (int i = 0; i < 2; ++i) {
    int o = i*4096 + t*16;
    int r = o >> 8;
    int s = (o >> 4) & 15;
    int xs = (s ^ (r & 15)) << 4;
    int row = r + ((xs >> 7) << 5);
    int db  = xs & 127;
    gload16(src + (size_t)row*ld + (db >> 1), dst + i*2048 + (t >> 6)*512);
  }
}

// ---------------- projection GEMM v3: z-batched {Q,K,V} in one launch ---------------
// Same r12 body (2-deep counted-vmcnt double-buffer, T3/T4); z selects operands.
// K/V (z>0): blocks whose 128-row M-tile is beyond nkp[b] exit immediately.
__global__ __launch_bounds__(256, 2) void gemm_proj3(const u16* __restrict__ qx,
                                                     const u16* __restrict__ kx,
                                                     const u16* __restrict__ vx,
                                                     const u16* __restrict__ Wt3,
                                                     const float* __restrict__ b0,
                                                     const float* __restrict__ b1,
                                                     const float* __restrict__ b2,
                                                     u16* __restrict__ o0,
                                                     u16* __restrict__ o1,
                                                     u16* __restrict__ o2,
                                                     const int* __restrict__ cnt) {
  int z = blockIdx.z;
  int m0 = blockIdx.x * 128, n0 = blockIdx.y * 128;
  if (z > 0) {
    int bb = m0 >> 11;
    if ((m0 & 2047) >= cnt[4 + bb]) return;   // dead compacted tile
  }
  const u16* A    = z == 0 ? qx : (z == 1 ? kx : vx);
  const u16* Bt   = Wt3 + (size_t)z * GN * GK;
  const float* bias = z == 0 ? b0 : (z == 1 ? b1 : b2);
  u16* outp       = z == 0 ? o0 : (z == 1 ? o1 : o2);
  float scale     = z == 0 ? QSCALE : 1.0f;
  int vmode       = (z == 2);

  __shared__ u16 Al[2][128*64];
  __shared__ u16 Bl[2][128*64];
  int t = threadIdx.x;
  int lane = t & 63, w = t >> 6;
  int wm = w >> 1, wn = w & 1;
  int g = lane >> 4, li = lane & 15;
  const u16* Ab0 = A + (size_t)m0 * GK;
  const u16* Bb0 = Bt + (size_t)n0 * GK;

  f32x4 acc[4][4];
  #pragma unroll
  for (int i = 0; i < 4; ++i)
    #pragma unroll
    for (int j = 0; j < 4; ++j) acc[i][j] = (f32x4){0.f,0.f,0.f,0.f};

  stage64(Al[0], Ab0,      GK, 4, t);
  stage64(Bl[0], Bb0,      GK, 4, t);
  stage64(Al[1], Ab0 + 64, GK, 4, t);
  stage64(Bl[1], Bb0 + 64, GK, 4, t);

  for (int kt = 0; kt < GK/64; ++kt) {
    int cur = kt & 1;
    if (kt < GK/64 - 1)
      asm volatile("s_waitcnt vmcnt(8)\n\ts_barrier" ::: "memory");
    else
      asm volatile("s_waitcnt vmcnt(0)\n\ts_barrier" ::: "memory");
    const u16* Ap = Al[cur];
    const u16* Bp = Bl[cur];
    #pragma unroll
    for (int kk = 0; kk < 2; ++kk) {
      s16x8 af[4], bfr[4];
      int cbase = kk*64 + (g << 4);
      #pragma unroll
      for (int mi = 0; mi < 4; ++mi) {
        int row = wm*64 + mi*16 + li;
        af[mi] = *(const s16x8*)(Ap + row*64 + ((cbase ^ ((row&7)<<4)) >> 1));
      }
      #pragma unroll
      for (int ni = 0; ni < 4; ++ni) {
        int row = wn*64 + ni*16 + li;
        bfr[ni] = *(const s16x8*)(Bp + row*64 + ((cbase ^ ((row&7)<<4)) >> 1));
      }
      #pragma unroll
      for (int mi = 0; mi < 4; ++mi)
        #pragma unroll
        for (int ni = 0; ni < 4; ++ni)
          acc[mi][ni] = __builtin_amdgcn_mfma_f32_16x16x32_bf16(af[mi], bfr[ni], acc[mi][ni], 0, 0, 0);
    }
    if (kt < GK/64 - 2) {
      asm volatile("s_barrier" ::: "memory");
      stage64(Al[cur], Ab0 + (kt+2)*64, GK, 4, t);
      stage64(Bl[cur], Bb0 + (kt+2)*64, GK, 4, t);
    }
  }

  #pragma unroll
  for (int ni = 0; ni < 4; ++ni) {
    int n = n0 + wn*64 + ni*16 + li;
    float bv = bias[n];
    int h = n >> 6, d = n & 63;
    #pragma unroll
    for (int mi = 0; mi < 4; ++mi) {
      int mrow = m0 + wm*64 + mi*16 + (g << 2);
      int bi = mrow >> 11, lr = mrow & 2047;
      if (!vmode) {
        u16* o = outp + ((size_t)(bi*NH + h)*LSEQ + lr)*HD + d;
        #pragma unroll
        for (int r2 = 0; r2 < 4; ++r2)
          o[(size_t)r2*HD] = f2bf((acc[mi][ni][r2] + bv) * scale);
      } else {
        u16* o = outp + ((size_t)(bi*NH + h)*HD + d)*LSEQ + lr;
        uint2 pk;
        pk.x = cvtpk((acc[mi][ni][0] + bv) * scale, (acc[mi][ni][1] + bv) * scale);
        pk.y = cvtpk((acc[mi][ni][2] + bv) * scale, (acc[mi][ni][3] + bv) * scale);
        *(uint2*)o = pk;
      }
    }
  }
}

// ---------------- flash attention v13 (r21 known-good): XCD-local K/V ---------------
// 32x32 MFMA, in-register P (T12), setprio (T5), counted vmcnt(4) pipeline (T4),
// paired-row conflict-free LDS, compacted keys, T1 grid transpose (bh fastest).
// KVBLK=64 is optimal: r22's KVBLK=128 raised VGPR 84->120 and dropped occupancy
// 22->17% (attn 69->77 us). __launch_bounds__(256,3): empirical VGPR cap =
// 256/min_waves (arg4 spills [r8,r14]).
__global__ __launch_bounds__(256, 3) void attn_kernel(const u16* __restrict__ Qb,
                                                      const u16* __restrict__ Kb,
                                                      const u16* __restrict__ Vt,
                                                      const int* __restrict__ cnt,
                                                      float* __restrict__ out) {
  __shared__ u16 Kl[2][64*64];
  __shared__ u16 Vl[2][64*64];
  int t = threadIdx.x;
  int lane = t & 63, w = t >> 6;
  int q = lane & 31, hi = lane >> 5;
  int bh = blockIdx.x, b = bh >> 4, h = bh & 15;   // T1: bh fastest -> same-KV
  int q0 = blockIdx.y * 128;                       //     blocks land on one XCD
  int nk  = cnt[b];
  int nkp = cnt[4 + b];
  int nt  = nkp >> 6;                        // >= 2 always (nkp >= 128)
  const u16* Qp = Qb + (size_t)bh * LSEQ * HD;
  const u16* Kp = Kb + (size_t)bh * LSEQ * HD;
  const u16* Vp = Vt + (size_t)bh * HD * LSEQ;

  int qrow = q0 + w*32 + q;
  s16x8 bq[4];
  #pragma unroll
  for (int ks = 0; ks < 4; ++ks)
    bq[ks] = *(const s16x8*)(Qp + (size_t)qrow*HD + ks*16 + hi*8);

  float lsum = 0.f;
  f32x16 acco[2];
  #pragma unroll
  for (int dt = 0; dt < 2; ++dt) acco[dt] = (f32x16){0.f};

  // paired-row frag offsets: byte = q*256 + ((half*128 + ks*32 + hi*16) ^ ((q&15)<<4))
  int koff[2][4];
  {
    int swz = (q & 15) << 4;
    #pragma unroll
    for (int half = 0; half < 2; ++half)
      #pragma unroll
      for (int ks = 0; ks < 4; ++ks)
        koff[half][ks] = q*256 + ((half*128 + ks*32 + hi*16) ^ swz);
  }

  // prologue: 2-deep K/V prefetch. FIFO/thread: [stage0:4][stage1:4]
  stage256(Kl[0], Kp, HD, t);
  stage256(Vl[0], Vp, LSEQ, t);
  stage256(Kl[1], Kp + (size_t)64*HD, HD, t);
  stage256(Vl[1], Vp + 64, LSEQ, t);

  auto body = [&](int tt, bool last) {
    int cur = tt & 1;
    int t0 = tt*64;

    if (last)
      asm volatile("s_waitcnt vmcnt(0)\n\ts_barrier" ::: "memory");
    else
      asm volatile("s_waitcnt vmcnt(4)\n\ts_barrier" ::: "memory");

    const char* Kc = (const char*)Kl[cur];
    const char* Vc = (const char*)Vl[cur];

    s16x8 ak[2][4];
    #pragma unroll
    for (int kt = 0; kt < 2; ++kt)
      #pragma unroll
      for (int ks = 0; ks < 4; ++ks)
        ak[kt][ks] = *(const s16x8*)(Kc + koff[kt][ks]);

    f32x16 S[2];
    __builtin_amdgcn_s_setprio(1);
    #pragma unroll
    for (int kt = 0; kt < 2; ++kt) {
      f32x16 z = {0.f};
      z = __builtin_amdgcn_mfma_f32_32x32x16_bf16(ak[kt][0], bq[0], z, 0, 0, 0);
      z = __builtin_amdgcn_mfma_f32_32x32x16_bf16(ak[kt][1], bq[1], z, 0, 0, 0);
      z = __builtin_amdgcn_mfma_f32_32x32x16_bf16(ak[kt][2], bq[2], z, 0, 0, 0);
      S[kt] = __builtin_amdgcn_mfma_f32_32x32x16_bf16(ak[kt][3], bq[3], z, 0, 0, 0);
    }
    __builtin_amdgcn_s_setprio(0);

    s16x8 av[2][4];
    #pragma unroll
    for (int dt = 0; dt < 2; ++dt)
      #pragma unroll
      for (int ks = 0; ks < 4; ++ks)
        av[dt][ks] = *(const s16x8*)(Vc + koff[dt][ks]);

    // softmax: p = exp2(S) directly; tail tiles zero pad keys via kA < nk
    bool nm = (t0 + 64 > nk);
    s16x8 pb[4];
    #pragma unroll
    for (int kt = 0; kt < 2; ++kt) {
      float p[16];
      #pragma unroll
      for (int r = 0; r < 16; ++r) {
        float e = exp2f_fast(S[kt][r]);
        if (nm) {
          int kA = t0 + kt*32 + ((r>>2)<<3) + (r&3) + (hi<<2);
          e = (kA < nk) ? e : 0.f;
        }
        p[r] = e;
      }
      float a0 = (p[0]+p[1])+(p[2]+p[3]);
      float a1 = (p[4]+p[5])+(p[6]+p[7]);
      float a2 = (p[8]+p[9])+(p[10]+p[11]);
      float a3 = (p[12]+p[13])+(p[14]+p[15]);
      lsum += (a0+a1)+(a2+a3);
      u32 w0 = cvtpk(p[0],  p[1]),  w1 = cvtpk(p[2],  p[3]);
      u32 w2 = cvtpk(p[4],  p[5]),  w3 = cvtpk(p[6],  p[7]);
      u32 w4 = cvtpk(p[8],  p[9]),  w5 = cvtpk(p[10], p[11]);
      u32 w6 = cvtpk(p[12], p[13]), w7 = cvtpk(p[14], p[15]);
      pswap(w0, w2); pswap(w1, w3);    // slice 2kt:   keys hi*8 + 0..7
      pswap(w4, w6); pswap(w5, w7);    // slice 2kt+1: keys 16 + hi*8 + 0..7
      union { u32 u[4]; s16x8 v; } f0, f1;
      f0.u[0] = w0; f0.u[1] = w1; f0.u[2] = w2; f0.u[3] = w3;
      f1.u[0] = w4; f1.u[1] = w5; f1.u[2] = w6; f1.u[3] = w7;
      pb[2*kt]   = f0.v;
      pb[2*kt+1] = f1.v;
    }

    __builtin_amdgcn_s_setprio(1);
    #pragma unroll
    for (int dt = 0; dt < 2; ++dt) {
      #pragma unroll
      for (int ks = 0; ks < 4; ++ks)
        acco[dt] = __builtin_amdgcn_mfma_f32_32x32x16_bf16(av[dt][ks], pb[ks], acco[dt], 0, 0, 0);
    }
    __builtin_amdgcn_s_setprio(0);

    if (!last) {
      if (tt + 2 < nt) {
        asm volatile("s_barrier" ::: "memory");
        int t0n = t0 + 128;
        stage256(Kl[cur], Kp + (size_t)t0n*HD, HD, t);
        stage256(Vl[cur], Vp + t0n, LSEQ, t);
      }
    }
  };

  for (int tt = 0; tt < nt - 1; ++tt) body(tt, false);
  body(nt - 1, true);

  float tot = lsum + __shfl_xor(lsum, 32);
  float inv = 1.0f / tot;
  float* op = out + ((size_t)b*LSEQ + qrow)*GN + h*HD;
  #pragma unroll
  for (int dt = 0; dt < 2; ++dt)
    #pragma unroll
    for (int rb = 0; rb < 4; ++rb) {
      float4 o;
      o.x = acco[dt][4*rb+0]*inv; o.y = acco[dt][4*rb+1]*inv;
      o.z = acco[dt][4*rb+2]*inv; o.w = acco[dt][4*rb+3]*inv;
      *(float4*)(op + dt*32 + rb*8 + hi*4) = o;
    }
}

// ---------------- host ----------------
extern "C" void kernel_launch(void* const* d_in, const int* in_sizes, int n_in,
                              void* d_out, int out_size, void* d_ws, size_t ws_size,
                              hipStream_t stream) {
  const float* query = (const float*)d_in[0];
  const float* key   = (const float*)d_in[1];
  const float* value = (const float*)d_in[2];
  const int*   masks = (const int*)d_in[3];
  const float* Wq = (const float*)d_in[4];
  const float* bq = (const float*)d_in[5];
  const float* Wk = (const float*)d_in[6];
  const float* bk = (const float*)d_in[7];
  const float* Wv = (const float*)d_in[8];
  const float* bv = (const float*)d_in[9];
  float* out = (float*)d_out;

  char* ws = (char*)d_ws;
  u16* qx  = (u16*)ws;                        // 16777216 B  Q bf16 [B,L,E]
  u16* kx  = (u16*)(ws + 16777216);           // 16777216 B  K bf16 compacted rows
  u16* wt3 = (u16*)(ws + 33554432);           //  6291456 B  [3][1024][1024] bf16
  u16* qb  = (u16*)(ws + 39845888);           // 16777216 B  [B,H,L,D]
  u16* kb  = (u16*)(ws + 56623104);           // 16777216 B  [B,H,L,D] (compacted)
  u16* vt  = (u16*)(ws + 73400320);           // 16777216 B  [B,H,D,L] (compacted)
  u16* vx  = (u16*)(ws + 90177536);           // 16777216 B  V bf16 compacted rows
  u16* idx = (u16*)(ws + 106954752);          //    16384 B  [4][2048]
  int* cnt = (int*)(ws + 106971136);          //       32 B  nk[4], nkp[4]
  (void)ws_size;

  prep_w_mask<<<4 + 1536, 256, 0, stream>>>(masks, Wq, Wk, Wv, idx, cnt, wt3);
  prep_inputs<<<4096 + 8192, 256, 0, stream>>>(query, key, value, idx, cnt,
                                               qx, kx, vx);
  gemm_proj3<<<dim3(GM/128, GN/128, 3), 256, 0, stream>>>(qx, kx, vx, wt3,
                                                          bq, bk, bv,
                                                          qb, kb, vt, cnt);
  attn_kernel<<<dim3(NB*NH, LSEQ/128), 256, 0, stream>>>(qb, kb, vt, cnt, out);
}